// Round 4
// baseline (371.066 us; speedup 1.0000x reference)
//
#include <hip/hip_runtime.h>
#include <hip/hip_bf16.h>
#include <stdint.h>

typedef __hip_bfloat16 bf16;
typedef short v8s __attribute__((ext_vector_type(8)));
typedef float v4f __attribute__((ext_vector_type(4)));

// Shape fixed by setup_inputs: B=4, T=2048, D=1024, H=16, hd=64, n=1024.
#define TT   2048
#define DD   1024
#define HH   16
#define HDIM 64
#define NN   1024
#define MASKV (-1e9f)
// q scale = hd^-0.5 * log2(e): softmax p = exp2(score) == e^{qk/sqrt(hd)}
#define QSCALE 0.18033688011112042f

#if __has_builtin(__builtin_amdgcn_exp2f)
#define EXP2F(x) __builtin_amdgcn_exp2f(x)
#else
#define EXP2F(x) exp2f(x)
#endif

__device__ __forceinline__ v4f mfma16x16x32(v8s a, v8s b, v4f c) {
    return __builtin_amdgcn_mfma_f32_16x16x32_bf16(a, b, c, 0, 0, 0);
}

#define GLDS16(lds, g)                                                          \
    __builtin_amdgcn_global_load_lds(                                           \
        (const __attribute__((address_space(1))) void*)(g),                     \
        (__attribute__((address_space(3))) void*)(lds), 16, 0, 0)

__device__ __forceinline__ bf16 f2b(float f) { return __float2bfloat16(f); }

// ---------------------------------------------------------------------------
// x (fp32, 8192x1024) -> bf16
// ---------------------------------------------------------------------------
__global__ __launch_bounds__(256) void cast_x(const float* __restrict__ x,
                                              bf16* __restrict__ xb)
{
    const size_t i = ((size_t)blockIdx.x * 256 + threadIdx.x) * 4;
    const float4 f = *(const float4*)(x + i);
    union { bf16 b[4]; uint64_t u; } cv;
    cv.b[0] = f2b(f.x); cv.b[1] = f2b(f.y); cv.b[2] = f2b(f.z); cv.b[3] = f2b(f.w);
    *(uint64_t*)(xb + i) = cv.u;
}

// ---------------------------------------------------------------------------
// Transpose+cast 4x (1024x1024) fp32 weights -> bf16 dst[z*1M + n*1024 + k]
// ---------------------------------------------------------------------------
__global__ __launch_bounds__(256) void transpose_w(
    const float* __restrict__ w0, const float* __restrict__ w1,
    const float* __restrict__ w2, const float* __restrict__ w3,
    bf16* __restrict__ dst)
{
    __shared__ float tile[64][65];
    const float* src = (blockIdx.z == 0) ? w0 : (blockIdx.z == 1) ? w1
                      : (blockIdx.z == 2) ? w2 : w3;
    bf16* d = dst + (size_t)blockIdx.z * 1024 * 1024;
    const int r0 = blockIdx.y * 64, c0 = blockIdx.x * 64;
    const int tx = threadIdx.x, ty = threadIdx.y;
#pragma unroll
    for (int j = 0; j < 16; j++) {
        int r = ty + j * 4;
        tile[r][tx] = src[(size_t)(r0 + r) * 1024 + c0 + tx];
    }
    __syncthreads();
#pragma unroll
    for (int j = 0; j < 16; j++) {
        int r = ty + j * 4;
        d[(size_t)(c0 + r) * 1024 + r0 + tx] = f2b(tile[tx][r]);
    }
}

// ---------------------------------------------------------------------------
// V transpose per (b,h): vtmp[bh][t][d] -> vt[bh][d][t]
// ---------------------------------------------------------------------------
__global__ __launch_bounds__(256) void transpose_v(
    const bf16* __restrict__ vtmp, bf16* __restrict__ vt)
{
    __shared__ bf16 tile[64][66];
    const int bh = blockIdx.y, t0 = blockIdx.x * 64;
    const int tx = threadIdx.x, ty = threadIdx.y;
    const bf16* src = vtmp + (size_t)bh * TT * HDIM;
    bf16* dst = vt + (size_t)bh * HDIM * TT;
#pragma unroll
    for (int j = 0; j < 16; j++) {
        int r = ty + j * 4;
        tile[r][tx] = src[(size_t)(t0 + r) * HDIM + tx];
    }
    __syncthreads();
#pragma unroll
    for (int j = 0; j < 16; j++) {
        int r = ty + j * 4;
        dst[(size_t)r * TT + t0 + tx] = tile[tx][r];
    }
}

// ---------------------------------------------------------------------------
// QKV GEMM: C = xb(8192x1024) * wqkvT(3072x1024)^T, tile 128x128x32.
// ---------------------------------------------------------------------------
__global__ __launch_bounds__(256) void gemm_qkv(
    const bf16* __restrict__ A, const bf16* __restrict__ BT,
    const float* __restrict__ bq, const float* __restrict__ bk,
    const float* __restrict__ bv,
    bf16* __restrict__ qo, bf16* __restrict__ ko, bf16* __restrict__ vo)
{
    __shared__ __align__(16) bf16 At[128 * 32];
    __shared__ __align__(16) bf16 Bt[128 * 32];
    const int tid  = threadIdx.x;
    const int lane = tid & 63, wave = tid >> 6;
    const int quad = lane >> 4, c = lane & 15;
    const int wm = wave >> 1, wn = wave & 1;
    const int m0 = blockIdx.y * 128, n0 = blockIdx.x * 128;
    const int K = 1024;
    const int chunkrow = lane >> 2;
    const int kseg     = (lane & 3) * 8;

    v4f acc[4][4];
#pragma unroll
    for (int i = 0; i < 4; i++)
#pragma unroll
        for (int j = 0; j < 4; j++) acc[i][j] = (v4f){0.f, 0.f, 0.f, 0.f};

    for (int k0 = 0; k0 < K; k0 += 32) {
#pragma unroll
        for (int ch = 0; ch < 2; ch++) {
            const int chunk = wave * 2 + ch;
            const int row   = chunk * 16 + chunkrow;
            GLDS16(At + chunk * 512, A  + (size_t)(m0 + row) * K + k0 + kseg);
            GLDS16(Bt + chunk * 512, BT + (size_t)(n0 + row) * K + k0 + kseg);
        }
        asm volatile("s_waitcnt vmcnt(0)" ::: "memory");
        __syncthreads();

        v8s af[4], bfr[4];
#pragma unroll
        for (int mt = 0; mt < 4; mt++)
            af[mt] = *(const v8s*)(At + (wm * 64 + mt * 16 + c) * 32 + quad * 8);
#pragma unroll
        for (int nt = 0; nt < 4; nt++)
            bfr[nt] = *(const v8s*)(Bt + (wn * 64 + nt * 16 + c) * 32 + quad * 8);
#pragma unroll
        for (int mt = 0; mt < 4; mt++)
#pragma unroll
            for (int nt = 0; nt < 4; nt++)
                acc[mt][nt] = mfma16x16x32(af[mt], bfr[nt], acc[mt][nt]);
        __syncthreads();
    }

#pragma unroll
    for (int mt = 0; mt < 4; mt++)
#pragma unroll
        for (int nt = 0; nt < 4; nt++) {
            const int col    = n0 + wn * 64 + nt * 16 + c;   // 0..3071
            const int type   = col >> 10;
            const int within = col & 1023;
            const int h = within >> 6, d = within & 63;
            const float* bp = (type == 0) ? bq : (type == 1) ? bk : bv;
            const float bias = bp[within];
#pragma unroll
            for (int r = 0; r < 4; r++) {
                const int row = m0 + wm * 64 + mt * 16 + quad * 4 + r;
                const int b_ = row >> 11, t = row & 2047;
                const int bh = b_ * HH + h;
                float v = acc[mt][nt][r] + bias;
                size_t idx = ((size_t)bh * TT + t) * HDIM + d;
                if (type == 0)      qo[idx] = f2b(v * QSCALE);
                else if (type == 1) ko[idx] = f2b(v);
                else                vo[idx] = f2b(v);
            }
        }
}

// ---------------------------------------------------------------------------
// Output GEMM: out = ctx(8192x1024) * woT(1024x1024)^T + bo, fp32 out.
// ---------------------------------------------------------------------------
__global__ __launch_bounds__(256) void gemm_out(
    const bf16* __restrict__ A, const bf16* __restrict__ BT,
    const float* __restrict__ bo, float* __restrict__ out)
{
    __shared__ __align__(16) bf16 At[128 * 32];
    __shared__ __align__(16) bf16 Bt[128 * 32];
    const int tid  = threadIdx.x;
    const int lane = tid & 63, wave = tid >> 6;
    const int quad = lane >> 4, c = lane & 15;
    const int wm = wave >> 1, wn = wave & 1;
    const int m0 = blockIdx.y * 128, n0 = blockIdx.x * 128;
    const int K = 1024;
    const int chunkrow = lane >> 2;
    const int kseg     = (lane & 3) * 8;

    v4f acc[4][4];
#pragma unroll
    for (int i = 0; i < 4; i++)
#pragma unroll
        for (int j = 0; j < 4; j++) acc[i][j] = (v4f){0.f, 0.f, 0.f, 0.f};

    for (int k0 = 0; k0 < K; k0 += 32) {
#pragma unroll
        for (int ch = 0; ch < 2; ch++) {
            const int chunk = wave * 2 + ch;
            const int row   = chunk * 16 + chunkrow;
            GLDS16(At + chunk * 512, A  + (size_t)(m0 + row) * K + k0 + kseg);
            GLDS16(Bt + chunk * 512, BT + (size_t)(n0 + row) * K + k0 + kseg);
        }
        asm volatile("s_waitcnt vmcnt(0)" ::: "memory");
        __syncthreads();

        v8s af[4], bfr[4];
#pragma unroll
        for (int mt = 0; mt < 4; mt++)
            af[mt] = *(const v8s*)(At + (wm * 64 + mt * 16 + c) * 32 + quad * 8);
#pragma unroll
        for (int nt = 0; nt < 4; nt++)
            bfr[nt] = *(const v8s*)(Bt + (wn * 64 + nt * 16 + c) * 32 + quad * 8);
#pragma unroll
        for (int mt = 0; mt < 4; mt++)
#pragma unroll
            for (int nt = 0; nt < 4; nt++)
                acc[mt][nt] = mfma16x16x32(af[mt], bfr[nt], acc[mt][nt]);
        __syncthreads();
    }

#pragma unroll
    for (int mt = 0; mt < 4; mt++)
#pragma unroll
        for (int nt = 0; nt < 4; nt++) {
            const int col = n0 + wn * 64 + nt * 16 + c;
            const float bias = bo[col];
#pragma unroll
            for (int r = 0; r < 4; r++) {
                const int row = m0 + wm * 64 + mt * 16 + quad * 4 + r;
                out[(size_t)row * 1024 + col] = acc[mt][nt][r] + bias;
            }
        }
}

// ---------------------------------------------------------------------------
// BD3LM mask predicate (boundary chunks only).
// ---------------------------------------------------------------------------
__device__ __forceinline__ bool attend_ok(int q, int kv, int bs) {
    const bool x0q = q >= NN, x0k = kv >= NN;
    const int bq = x0q ? (q - NN) / bs : q / bs;
    const int bk = x0k ? (kv - NN) / bs : kv / bs;
    if (bq == bk && x0q == x0k) return true;
    if (x0k && !x0q && bq > bk) return true;
    if (x0k && x0q && bq >= bk) return true;
    return false;
}

// ---------------------------------------------------------------------------
// Flash attention v3: software-pipelined chunk loop (ping-pong K/V register
// prefetch), double-buffered P tile (one fence/chunk), wave-balanced q-tile
// pairs. grid 1024 = 64 bh x 16; block 256 = 4 waves. Wave slot w (0..63)
// handles tiles {w, 63-w} (xt) or {64+(w-32), 127-(w-32)} (x0): every wave
// ~33 chunks -> no drain imbalance.
// ---------------------------------------------------------------------------
__global__ __launch_bounds__(256, 4) void attn(
    const bf16* __restrict__ Q, const bf16* __restrict__ Kb,
    const bf16* __restrict__ VT, bf16* __restrict__ ctx,
    const int* __restrict__ bsp)
{
    __shared__ __align__(16) bf16 plds[4][2][16][32];
    const int bs = bsp[0];
    const int tid = threadIdx.x, lane = tid & 63, wv = tid >> 6;
    const int quad = lane >> 4, c = lane & 15;
    const int bh = blockIdx.x >> 4;
    const int w  = (blockIdx.x & 15) * 4 + wv;     // 0..63

    int tile0, tile1;
    if (w < 32) { tile0 = w;            tile1 = 63 - w;  }
    else        { tile0 = 32 + w;       tile1 = 159 - w; }   // 64+(w-32), 127-(w-32)

    const bf16* qp = Q  + (size_t)bh * TT * HDIM;
    const bf16* kp = Kb + (size_t)bh * TT * HDIM;
    const bf16* vp = VT + (size_t)bh * HDIM * TT;
    const int b_ = bh >> 4, h = bh & 15;

#pragma unroll 1
    for (int ti = 0; ti < 2; ti++) {
        const int q0 = ((ti == 0) ? tile0 : tile1) * 16;

        const v8s aq0 = *(const v8s*)(qp + (q0 + c) * HDIM + quad * 8);
        const v8s aq1 = *(const v8s*)(qp + (q0 + c) * HDIM + 32 + quad * 8);

        v4f O[4];
#pragma unroll
        for (int dt = 0; dt < 4; dt++) O[dt] = (v4f){0.f, 0.f, 0.f, 0.f};
        float lr[4] = {0.f, 0.f, 0.f, 0.f};

        // ---- chunk plan: [diag masked] [full unmasked] [boundary masked] ---
        int diag_lo = 0, n0 = 0, nfull, b_lo, b_hi;
        if (q0 < NN) {
            diag_lo = (bs * (q0 / bs)) & ~7;
            const int diag_hi = min(bs * ((q0 + 15) / bs) + bs, NN);
            n0 = (diag_hi - diag_lo + 31) >> 5;
            const int full_hi = NN + bs * (q0 / bs);
            nfull = (full_hi - NN) >> 5;
            b_lo  = NN + (nfull << 5);
            b_hi  = min(NN + bs * ((q0 + 15) / bs), 2 * NN);
        } else {
            const int q0l = q0 - NN;
            const int full_hi = NN + min(bs * (q0l / bs) + bs, NN);
            nfull = (full_hi - NN) >> 5;
            b_lo  = NN + (nfull << 5);
            b_hi  = min(NN + bs * ((q0l + 15) / bs) + bs, 2 * NN);
        }
        const int nb = (b_hi > b_lo) ? ((b_hi - b_lo + 31) >> 5) : 0;
        const int nc = n0 + nfull + nb;

        auto chunk_of = [&](int i, int& kb, int& lim) {
            if (i < n0)              { kb = diag_lo + (i << 5);              lim = NN;     }
            else if (i < n0 + nfull) { kb = NN + ((i - n0) << 5);            lim = 0;      }
            else                     { kb = b_lo + ((i - n0 - nfull) << 5);  lim = 2 * NN; }
        };
        auto loadKV = [&](int kb, v8s* K, v8s* V) {
            const bf16* kpp = kp + (size_t)kb * HDIM;
            K[0] = *(const v8s*)(kpp + c * HDIM + quad * 8);
            K[1] = *(const v8s*)(kpp + c * HDIM + 32 + quad * 8);
            K[2] = *(const v8s*)(kpp + (16 + c) * HDIM + quad * 8);
            K[3] = *(const v8s*)(kpp + (16 + c) * HDIM + 32 + quad * 8);
            const bf16* vpp = vp + kb + quad * 8;
            V[0] = *(const v8s*)(vpp + (size_t)c * TT);
            V[1] = *(const v8s*)(vpp + (size_t)(16 + c) * TT);
            V[2] = *(const v8s*)(vpp + (size_t)(32 + c) * TT);
            V[3] = *(const v8s*)(vpp + (size_t)(48 + c) * TT);
        };
        auto process = [&](int kb, int lim, int pbuf, const v8s* K, const v8s* V) {
            v4f Sa = (v4f){0.f, 0.f, 0.f, 0.f};
            v4f Sb = (v4f){0.f, 0.f, 0.f, 0.f};
            Sa = mfma16x16x32(aq0, K[0], Sa);
            Sa = mfma16x16x32(aq1, K[1], Sa);
            Sb = mfma16x16x32(aq0, K[2], Sb);
            Sb = mfma16x16x32(aq1, K[3], Sb);
#pragma unroll
            for (int r = 0; r < 4; r++) {
                float sa = Sa[r], sb = Sb[r];
                if (lim) {
                    const int q  = q0 + quad * 4 + r;
                    const int ka = kb + c, k2 = kb + 16 + c;
                    if (!(ka < lim && attend_ok(q, ka, bs))) sa = MASKV;
                    if (!(k2 < lim && attend_ok(q, k2, bs))) sb = MASKV;
                }
                const float pa = EXP2F(sa);
                const float pb = EXP2F(sb);
                lr[r] += pa + pb;
                plds[wv][pbuf][quad * 4 + r][c]      = f2b(pa);
                plds[wv][pbuf][quad * 4 + r][16 + c] = f2b(pb);
            }
            __threadfence_block();          // ds writes visible to own wave
            const v8s pf = *(const v8s*)(&plds[wv][pbuf][c][quad * 8]);
#pragma unroll
            for (int dt = 0; dt < 4; dt++)
                O[dt] = mfma16x16x32(pf, V[dt], O[dt]);
        };

        // ---- ping-pong software pipeline ----------------------------------
        v8s Ka[4], Va[4], Kc[4], Vc[4];
        int kb0, lim0, kb1, lim1;
        chunk_of(0, kb0, lim0);
        loadKV(kb0, Ka, Va);
        int i = 0;
        while (i < nc) {
            if (i + 1 < nc) { chunk_of(i + 1, kb1, lim1); loadKV(kb1, Kc, Vc); }
            process(kb0, lim0, 0, Ka, Va);
            i++;
            if (i >= nc) break;
            if (i + 1 < nc) { chunk_of(i + 1, kb0, lim0); loadKV(kb0, Ka, Va); }
            process(kb1, lim1, 1, Kc, Vc);
            i++;
        }

        // ---- denominator + ctx write --------------------------------------
#pragma unroll
        for (int r = 0; r < 4; r++) {
            float s = lr[r];
#pragma unroll
            for (int off = 1; off < 16; off <<= 1) s += __shfl_xor(s, off);
            const float inv = 1.0f / fmaxf(s, 1e-30f);
            const int t = q0 + quad * 4 + r;
#pragma unroll
            for (int dt = 0; dt < 4; dt++)
                ctx[((size_t)(b_ * TT + t)) * DD + h * 64 + dt * 16 + c] =
                    f2b(O[dt][r] * inv);
        }
    }
}

// ---------------------------------------------------------------------------
extern "C" void kernel_launch(void* const* d_in, const int* in_sizes, int n_in,
                              void* d_out, int out_size, void* d_ws, size_t ws_size,
                              hipStream_t stream)
{
    const float* x  = (const float*)d_in[0];
    const float* Wq = (const float*)d_in[1];
    const float* bq = (const float*)d_in[2];
    const float* Wk = (const float*)d_in[3];
    const float* bk = (const float*)d_in[4];
    const float* Wv = (const float*)d_in[5];
    const float* bv = (const float*)d_in[6];
    const float* Wo = (const float*)d_in[7];
    const float* bo = (const float*)d_in[8];
    const int*  bsp = (const int*)d_in[9];
    float* out = (float*)d_out;

    bf16* ws    = (bf16*)d_ws;
    bf16* xb    = ws;                           // reused as ctx after gemm_qkv
    bf16* wqkvT = xb + 8388608;
    bf16* woT   = wqkvT + 3 * 1024 * 1024;
    bf16* qbuf  = woT + 1024 * 1024;            // (bh,t,d)
    bf16* kbuf  = qbuf + 8388608;
    bf16* vtmp  = kbuf + 8388608;               // (bh,t,d)
    bf16* vt    = vtmp + 8388608;               // (bh,d,t)
    bf16* ctx   = xb;

    cast_x<<<8192, 256, 0, stream>>>(x, xb);
    transpose_w<<<dim3(16, 16, 4), dim3(64, 4), 0, stream>>>(Wq, Wk, Wv, Wo, wqkvT);
    gemm_qkv<<<dim3(24, 64), 256, 0, stream>>>(xb, wqkvT, bq, bk, bv,
                                               qbuf, kbuf, vtmp);
    transpose_v<<<dim3(32, 64), dim3(64, 4), 0, stream>>>(vtmp, vt);
    attn<<<1024, 256, 0, stream>>>(qbuf, kbuf, vt, ctx, bsp);
    gemm_out<<<dim3(8, 64), 256, 0, stream>>>(ctx, woT, bo, out);
}

// Round 5
// 339.878 us; speedup vs baseline: 1.0918x; 1.0918x over previous
//
#include <hip/hip_runtime.h>
#include <hip/hip_bf16.h>
#include <stdint.h>

typedef __hip_bfloat16 bf16;
typedef short v8s __attribute__((ext_vector_type(8)));
typedef float v4f __attribute__((ext_vector_type(4)));

// Shape fixed by setup_inputs: B=4, T=2048, D=1024, H=16, hd=64, n=1024.
#define TT   2048
#define DD   1024
#define HH   16
#define HDIM 64
#define NN   1024
#define MASKV (-1e9f)
// q scale = hd^-0.5 * log2(e): softmax p = exp2(score) == e^{qk/sqrt(hd)}
#define QSCALE 0.18033688011112042f

#if __has_builtin(__builtin_amdgcn_exp2f)
#define EXP2F(x) __builtin_amdgcn_exp2f(x)
#else
#define EXP2F(x) exp2f(x)
#endif

__device__ __forceinline__ v4f mfma16x16x32(v8s a, v8s b, v4f c) {
    return __builtin_amdgcn_mfma_f32_16x16x32_bf16(a, b, c, 0, 0, 0);
}

#define GLDS16(lds, g)                                                          \
    __builtin_amdgcn_global_load_lds(                                           \
        (const __attribute__((address_space(1))) void*)(g),                     \
        (__attribute__((address_space(3))) void*)(lds), 16, 0, 0)

__device__ __forceinline__ bf16 f2b(float f) { return __float2bfloat16(f); }

// ---------------------------------------------------------------------------
// x (fp32, 8192x1024) -> bf16
// ---------------------------------------------------------------------------
__global__ __launch_bounds__(256) void cast_x(const float* __restrict__ x,
                                              bf16* __restrict__ xb)
{
    const size_t i = ((size_t)blockIdx.x * 256 + threadIdx.x) * 4;
    const float4 f = *(const float4*)(x + i);
    union { bf16 b[4]; uint64_t u; } cv;
    cv.b[0] = f2b(f.x); cv.b[1] = f2b(f.y); cv.b[2] = f2b(f.z); cv.b[3] = f2b(f.w);
    *(uint64_t*)(xb + i) = cv.u;
}

// ---------------------------------------------------------------------------
// Transpose+cast 4x (1024x1024) fp32 weights -> bf16 dst[z*1M + n*1024 + k]
// ---------------------------------------------------------------------------
__global__ __launch_bounds__(256) void transpose_w(
    const float* __restrict__ w0, const float* __restrict__ w1,
    const float* __restrict__ w2, const float* __restrict__ w3,
    bf16* __restrict__ dst)
{
    __shared__ float tile[64][65];
    const float* src = (blockIdx.z == 0) ? w0 : (blockIdx.z == 1) ? w1
                      : (blockIdx.z == 2) ? w2 : w3;
    bf16* d = dst + (size_t)blockIdx.z * 1024 * 1024;
    const int r0 = blockIdx.y * 64, c0 = blockIdx.x * 64;
    const int tx = threadIdx.x, ty = threadIdx.y;
#pragma unroll
    for (int j = 0; j < 16; j++) {
        int r = ty + j * 4;
        tile[r][tx] = src[(size_t)(r0 + r) * 1024 + c0 + tx];
    }
    __syncthreads();
#pragma unroll
    for (int j = 0; j < 16; j++) {
        int r = ty + j * 4;
        d[(size_t)(c0 + r) * 1024 + r0 + tx] = f2b(tile[tx][r]);
    }
}

// ---------------------------------------------------------------------------
// V transpose per (b,h): vtmp[bh][t][d] -> vt[bh][d][t]
// ---------------------------------------------------------------------------
__global__ __launch_bounds__(256) void transpose_v(
    const bf16* __restrict__ vtmp, bf16* __restrict__ vt)
{
    __shared__ bf16 tile[64][66];
    const int bh = blockIdx.y, t0 = blockIdx.x * 64;
    const int tx = threadIdx.x, ty = threadIdx.y;
    const bf16* src = vtmp + (size_t)bh * TT * HDIM;
    bf16* dst = vt + (size_t)bh * HDIM * TT;
#pragma unroll
    for (int j = 0; j < 16; j++) {
        int r = ty + j * 4;
        tile[r][tx] = src[(size_t)(t0 + r) * HDIM + tx];
    }
    __syncthreads();
#pragma unroll
    for (int j = 0; j < 16; j++) {
        int r = ty + j * 4;
        dst[(size_t)r * TT + t0 + tx] = tile[tx][r];
    }
}

// ---------------------------------------------------------------------------
// QKV GEMM: C = xb(8192x1024) * wqkvT(3072x1024)^T, tile 128x128x32.
// ---------------------------------------------------------------------------
__global__ __launch_bounds__(256) void gemm_qkv(
    const bf16* __restrict__ A, const bf16* __restrict__ BT,
    const float* __restrict__ bq, const float* __restrict__ bk,
    const float* __restrict__ bv,
    bf16* __restrict__ qo, bf16* __restrict__ ko, bf16* __restrict__ vo)
{
    __shared__ __align__(16) bf16 At[128 * 32];
    __shared__ __align__(16) bf16 Bt[128 * 32];
    const int tid  = threadIdx.x;
    const int lane = tid & 63, wave = tid >> 6;
    const int quad = lane >> 4, c = lane & 15;
    const int wm = wave >> 1, wn = wave & 1;
    const int m0 = blockIdx.y * 128, n0 = blockIdx.x * 128;
    const int K = 1024;
    const int chunkrow = lane >> 2;
    const int kseg     = (lane & 3) * 8;

    v4f acc[4][4];
#pragma unroll
    for (int i = 0; i < 4; i++)
#pragma unroll
        for (int j = 0; j < 4; j++) acc[i][j] = (v4f){0.f, 0.f, 0.f, 0.f};

    for (int k0 = 0; k0 < K; k0 += 32) {
#pragma unroll
        for (int ch = 0; ch < 2; ch++) {
            const int chunk = wave * 2 + ch;
            const int row   = chunk * 16 + chunkrow;
            GLDS16(At + chunk * 512, A  + (size_t)(m0 + row) * K + k0 + kseg);
            GLDS16(Bt + chunk * 512, BT + (size_t)(n0 + row) * K + k0 + kseg);
        }
        asm volatile("s_waitcnt vmcnt(0)" ::: "memory");
        __syncthreads();

        v8s af[4], bfr[4];
#pragma unroll
        for (int mt = 0; mt < 4; mt++)
            af[mt] = *(const v8s*)(At + (wm * 64 + mt * 16 + c) * 32 + quad * 8);
#pragma unroll
        for (int nt = 0; nt < 4; nt++)
            bfr[nt] = *(const v8s*)(Bt + (wn * 64 + nt * 16 + c) * 32 + quad * 8);
#pragma unroll
        for (int mt = 0; mt < 4; mt++)
#pragma unroll
            for (int nt = 0; nt < 4; nt++)
                acc[mt][nt] = mfma16x16x32(af[mt], bfr[nt], acc[mt][nt]);
        __syncthreads();
    }

#pragma unroll
    for (int mt = 0; mt < 4; mt++)
#pragma unroll
        for (int nt = 0; nt < 4; nt++) {
            const int col    = n0 + wn * 64 + nt * 16 + c;   // 0..3071
            const int type   = col >> 10;
            const int within = col & 1023;
            const int h = within >> 6, d = within & 63;
            const float* bp = (type == 0) ? bq : (type == 1) ? bk : bv;
            const float bias = bp[within];
#pragma unroll
            for (int r = 0; r < 4; r++) {
                const int row = m0 + wm * 64 + mt * 16 + quad * 4 + r;
                const int b_ = row >> 11, t = row & 2047;
                const int bh = b_ * HH + h;
                float v = acc[mt][nt][r] + bias;
                size_t idx = ((size_t)bh * TT + t) * HDIM + d;
                if (type == 0)      qo[idx] = f2b(v * QSCALE);
                else if (type == 1) ko[idx] = f2b(v);
                else                vo[idx] = f2b(v);
            }
        }
}

// ---------------------------------------------------------------------------
// Output GEMM: out = ctx(8192x1024) * woT(1024x1024)^T + bo, fp32 out.
// ---------------------------------------------------------------------------
__global__ __launch_bounds__(256) void gemm_out(
    const bf16* __restrict__ A, const bf16* __restrict__ BT,
    const float* __restrict__ bo, float* __restrict__ out)
{
    __shared__ __align__(16) bf16 At[128 * 32];
    __shared__ __align__(16) bf16 Bt[128 * 32];
    const int tid  = threadIdx.x;
    const int lane = tid & 63, wave = tid >> 6;
    const int quad = lane >> 4, c = lane & 15;
    const int wm = wave >> 1, wn = wave & 1;
    const int m0 = blockIdx.y * 128, n0 = blockIdx.x * 128;
    const int K = 1024;
    const int chunkrow = lane >> 2;
    const int kseg     = (lane & 3) * 8;

    v4f acc[4][4];
#pragma unroll
    for (int i = 0; i < 4; i++)
#pragma unroll
        for (int j = 0; j < 4; j++) acc[i][j] = (v4f){0.f, 0.f, 0.f, 0.f};

    for (int k0 = 0; k0 < K; k0 += 32) {
#pragma unroll
        for (int ch = 0; ch < 2; ch++) {
            const int chunk = wave * 2 + ch;
            const int row   = chunk * 16 + chunkrow;
            GLDS16(At + chunk * 512, A  + (size_t)(m0 + row) * K + k0 + kseg);
            GLDS16(Bt + chunk * 512, BT + (size_t)(n0 + row) * K + k0 + kseg);
        }
        asm volatile("s_waitcnt vmcnt(0)" ::: "memory");
        __syncthreads();

        v8s af[4], bfr[4];
#pragma unroll
        for (int mt = 0; mt < 4; mt++)
            af[mt] = *(const v8s*)(At + (wm * 64 + mt * 16 + c) * 32 + quad * 8);
#pragma unroll
        for (int nt = 0; nt < 4; nt++)
            bfr[nt] = *(const v8s*)(Bt + (wn * 64 + nt * 16 + c) * 32 + quad * 8);
#pragma unroll
        for (int mt = 0; mt < 4; mt++)
#pragma unroll
            for (int nt = 0; nt < 4; nt++)
                acc[mt][nt] = mfma16x16x32(af[mt], bfr[nt], acc[mt][nt]);
        __syncthreads();
    }

#pragma unroll
    for (int mt = 0; mt < 4; mt++)
#pragma unroll
        for (int nt = 0; nt < 4; nt++) {
            const int col = n0 + wn * 64 + nt * 16 + c;
            const float bias = bo[col];
#pragma unroll
            for (int r = 0; r < 4; r++) {
                const int row = m0 + wm * 64 + mt * 16 + quad * 4 + r;
                out[(size_t)row * 1024 + col] = acc[mt][nt][r] + bias;
            }
        }
}

// ---------------------------------------------------------------------------
// BD3LM mask predicate (masked chunks only).
// ---------------------------------------------------------------------------
__device__ __forceinline__ bool attend_ok(int q, int kv, int bs) {
    const bool x0q = q >= NN, x0k = kv >= NN;
    const int bq = x0q ? (q - NN) / bs : q / bs;
    const int bk = x0k ? (kv - NN) / bs : kv / bs;
    if (bq == bk && x0q == x0k) return true;
    if (x0k && !x0q && bq > bk) return true;
    if (x0k && x0q && bq >= bk) return true;
    return false;
}

// ---------------------------------------------------------------------------
// Flash attention v4: block = (bh, 64-row q-group pair). 4 waves each own one
// 16-row tile of the group and iterate the SAME chunk sequence (union of the
// 4 tiles' ranges) -> identical K/V addresses across waves = L1/L2 temporal
// sharing (~4x traffic cut vs per-tile waves). Group pairing {P, 31-P} makes
// per-block work constant (~41 chunks) -> zero drain imbalance.
// grid 1024 = 64 bh x 16 pairs; 4 blocks/CU, 4 waves/SIMD.
// No register ping-pong (v3's spilled); P tile double-buffered by parity.
// ---------------------------------------------------------------------------
__global__ __launch_bounds__(256, 4) void attn(
    const bf16* __restrict__ Q, const bf16* __restrict__ Kb,
    const bf16* __restrict__ VT, bf16* __restrict__ ctx,
    const int* __restrict__ bsp)
{
    __shared__ __align__(16) bf16 plds[4][2][16][32];
    const int bs = bsp[0];
    const int tid = threadIdx.x, lane = tid & 63, wv = tid >> 6;
    const int quad = lane >> 4, c = lane & 15;
    const int bh = blockIdx.x >> 4;
    const int P  = blockIdx.x & 15;

    const bf16* qp = Q  + (size_t)bh * TT * HDIM;
    const bf16* kp = Kb + (size_t)bh * TT * HDIM;
    const bf16* vp = VT + (size_t)bh * HDIM * TT;
    const int b_ = bh >> 4, h = bh & 15;

#pragma unroll 1
    for (int sel = 0; sel < 2; sel++) {
        const int grp  = (sel == 0) ? P : 31 - P;       // 0..15 xt, 16..31 x0
        const bool xt  = grp < 16;
        const int q0g  = xt ? grp * 64 : NN + (grp - 16) * 64;
        const int q0   = q0g + wv * 16;                  // this wave's tile

        // ---- chunk plan for the whole 64-row group (wave-uniform) ----------
        int d_lo = 0, nd = 0, nf, b_lo, nb;
        if (xt) {
            d_lo = (bs * (q0g / bs)) & ~31;
            const int d_hi = min((bs * ((q0g + 63) / bs) + bs + 31) & ~31, NN);
            nd = (d_hi - d_lo) >> 5;
            const int f_hi = NN + bs * (q0g / bs);       // bk < bq_min: full
            nf = (f_hi - NN) >> 5;                        // floor to chunks
            b_lo = NN + (nf << 5);
            const int b_hi = min((NN + bs * ((q0g + 63) / bs) + 31) & ~31, 2 * NN);
            nb = (b_hi > b_lo) ? (b_hi - b_lo) >> 5 : 0;
        } else {
            const int q0l = q0g - NN;
            const int f_hi = NN + min(bs * (q0l / bs) + bs, NN);  // bk <= bq_min
            nf = (f_hi - NN) >> 5;
            b_lo = NN + (nf << 5);
            const int b_hi =
                min((NN + bs * ((q0l + 63) / bs) + bs + 31) & ~31, 2 * NN);
            nb = (b_hi > b_lo) ? (b_hi - b_lo) >> 5 : 0;
        }
        const int nc = nd + nf + nb;

        const v8s aq0 = *(const v8s*)(qp + (q0 + c) * HDIM + quad * 8);
        const v8s aq1 = *(const v8s*)(qp + (q0 + c) * HDIM + 32 + quad * 8);

        v4f O[4];
#pragma unroll
        for (int dt = 0; dt < 4; dt++) O[dt] = (v4f){0.f, 0.f, 0.f, 0.f};
        float lr[4] = {0.f, 0.f, 0.f, 0.f};

#pragma unroll 1
        for (int i = 0; i < nc; i++) {
            int kb, lim;
            if (i < nd)           { kb = d_lo + (i << 5);             lim = NN;     }
            else if (i < nd + nf) { kb = NN + ((i - nd) << 5);        lim = 0;      }
            else                  { kb = b_lo + ((i - nd - nf) << 5); lim = 2 * NN; }

            const bf16* kpp = kp + (size_t)kb * HDIM;
            const v8s k0a = *(const v8s*)(kpp + c * HDIM + quad * 8);
            const v8s k0b = *(const v8s*)(kpp + c * HDIM + 32 + quad * 8);
            const v8s k1a = *(const v8s*)(kpp + (16 + c) * HDIM + quad * 8);
            const v8s k1b = *(const v8s*)(kpp + (16 + c) * HDIM + 32 + quad * 8);
            v4f Sa = (v4f){0.f, 0.f, 0.f, 0.f};
            v4f Sb = (v4f){0.f, 0.f, 0.f, 0.f};
            Sa = mfma16x16x32(aq0, k0a, Sa);
            Sa = mfma16x16x32(aq1, k0b, Sa);
            Sb = mfma16x16x32(aq0, k1a, Sb);
            Sb = mfma16x16x32(aq1, k1b, Sb);

            const int pbuf = i & 1;
#pragma unroll
            for (int r = 0; r < 4; r++) {
                float sa = Sa[r], sb = Sb[r];
                if (lim) {
                    const int q  = q0 + quad * 4 + r;
                    const int ka = kb + c, k2 = kb + 16 + c;
                    if (!(ka < lim && attend_ok(q, ka, bs))) sa = MASKV;
                    if (!(k2 < lim && attend_ok(q, k2, bs))) sb = MASKV;
                }
                const float pa = EXP2F(sa);
                const float pb = EXP2F(sb);
                lr[r] += pa + pb;
                plds[wv][pbuf][quad * 4 + r][c]      = f2b(pa);
                plds[wv][pbuf][quad * 4 + r][16 + c] = f2b(pb);
            }
            __threadfence_block();          // wave-local: drain ds writes
            const v8s pf = *(const v8s*)(&plds[wv][pbuf][c][quad * 8]);
            const bf16* vpp = vp + kb + quad * 8;
#pragma unroll
            for (int dt = 0; dt < 4; dt++) {
                const v8s vf = *(const v8s*)(vpp + (size_t)(dt * 16 + c) * TT);
                O[dt] = mfma16x16x32(pf, vf, O[dt]);
            }
        }

        // ---- denominator + ctx write ---------------------------------------
#pragma unroll
        for (int r = 0; r < 4; r++) {
            float s = lr[r];
#pragma unroll
            for (int off = 1; off < 16; off <<= 1) s += __shfl_xor(s, off);
            const float inv = 1.0f / fmaxf(s, 1e-30f);
            const int t = q0 + quad * 4 + r;
#pragma unroll
            for (int dt = 0; dt < 4; dt++)
                ctx[((size_t)(b_ * TT + t)) * DD + h * 64 + dt * 16 + c] =
                    f2b(O[dt][r] * inv);
        }
    }
}

// ---------------------------------------------------------------------------
extern "C" void kernel_launch(void* const* d_in, const int* in_sizes, int n_in,
                              void* d_out, int out_size, void* d_ws, size_t ws_size,
                              hipStream_t stream)
{
    const float* x  = (const float*)d_in[0];
    const float* Wq = (const float*)d_in[1];
    const float* bq = (const float*)d_in[2];
    const float* Wk = (const float*)d_in[3];
    const float* bk = (const float*)d_in[4];
    const float* Wv = (const float*)d_in[5];
    const float* bv = (const float*)d_in[6];
    const float* Wo = (const float*)d_in[7];
    const float* bo = (const float*)d_in[8];
    const int*  bsp = (const int*)d_in[9];
    float* out = (float*)d_out;

    bf16* ws    = (bf16*)d_ws;
    bf16* xb    = ws;                           // reused as ctx after gemm_qkv
    bf16* wqkvT = xb + 8388608;
    bf16* woT   = wqkvT + 3 * 1024 * 1024;
    bf16* qbuf  = woT + 1024 * 1024;            // (bh,t,d)
    bf16* kbuf  = qbuf + 8388608;
    bf16* vtmp  = kbuf + 8388608;               // (bh,t,d)
    bf16* vt    = vtmp + 8388608;               // (bh,d,t)
    bf16* ctx   = xb;

    cast_x<<<8192, 256, 0, stream>>>(x, xb);
    transpose_w<<<dim3(16, 16, 4), dim3(64, 4), 0, stream>>>(Wq, Wk, Wv, Wo, wqkvT);
    gemm_qkv<<<dim3(24, 64), 256, 0, stream>>>(xb, wqkvT, bq, bk, bv,
                                               qbuf, kbuf, vtmp);
    transpose_v<<<dim3(32, 64), dim3(64, 4), 0, stream>>>(vtmp, vt);
    attn<<<1024, 256, 0, stream>>>(qbuf, kbuf, vt, ctx, bsp);
    gemm_out<<<dim3(8, 64), 256, 0, stream>>>(ctx, woT, bo, out);
}

// Round 6
// 284.108 us; speedup vs baseline: 1.3061x; 1.1963x over previous
//
#include <hip/hip_runtime.h>
#include <hip/hip_bf16.h>
#include <stdint.h>

typedef __hip_bfloat16 bf16;
typedef short v8s __attribute__((ext_vector_type(8)));
typedef float v4f __attribute__((ext_vector_type(4)));

// Shape fixed by setup_inputs: B=4, T=2048, D=1024, H=16, hd=64, n=1024.
#define TT   2048
#define DD   1024
#define HH   16
#define HDIM 64
#define NN   1024
#define MASKV (-1e9f)
// q scale = hd^-0.5 * log2(e): softmax p = exp2(score) == e^{qk/sqrt(hd)}
#define QSCALE 0.18033688011112042f

#if __has_builtin(__builtin_amdgcn_exp2f)
#define EXP2F(x) __builtin_amdgcn_exp2f(x)
#else
#define EXP2F(x) exp2f(x)
#endif

__device__ __forceinline__ v4f mfma16x16x32(v8s a, v8s b, v4f c) {
    return __builtin_amdgcn_mfma_f32_16x16x32_bf16(a, b, c, 0, 0, 0);
}

#define GLDS16(lds, g)                                                          \
    __builtin_amdgcn_global_load_lds(                                           \
        (const __attribute__((address_space(1))) void*)(g),                     \
        (__attribute__((address_space(3))) void*)(lds), 16, 0, 0)

__device__ __forceinline__ bf16 f2b(float f) { return __float2bfloat16(f); }

// ---------------------------------------------------------------------------
// x (fp32, 8192x1024) -> bf16
// ---------------------------------------------------------------------------
__global__ __launch_bounds__(256) void cast_x(const float* __restrict__ x,
                                              bf16* __restrict__ xb)
{
    const size_t i = ((size_t)blockIdx.x * 256 + threadIdx.x) * 4;
    const float4 f = *(const float4*)(x + i);
    union { bf16 b[4]; uint64_t u; } cv;
    cv.b[0] = f2b(f.x); cv.b[1] = f2b(f.y); cv.b[2] = f2b(f.z); cv.b[3] = f2b(f.w);
    *(uint64_t*)(xb + i) = cv.u;
}

// ---------------------------------------------------------------------------
// Transpose+cast 4x (1024x1024) fp32 weights -> bf16 dst[z*1M + n*1024 + k]
// ---------------------------------------------------------------------------
__global__ __launch_bounds__(256) void transpose_w(
    const float* __restrict__ w0, const float* __restrict__ w1,
    const float* __restrict__ w2, const float* __restrict__ w3,
    bf16* __restrict__ dst)
{
    __shared__ float tile[64][65];
    const float* src = (blockIdx.z == 0) ? w0 : (blockIdx.z == 1) ? w1
                      : (blockIdx.z == 2) ? w2 : w3;
    bf16* d = dst + (size_t)blockIdx.z * 1024 * 1024;
    const int r0 = blockIdx.y * 64, c0 = blockIdx.x * 64;
    const int tx = threadIdx.x, ty = threadIdx.y;
#pragma unroll
    for (int j = 0; j < 16; j++) {
        int r = ty + j * 4;
        tile[r][tx] = src[(size_t)(r0 + r) * 1024 + c0 + tx];
    }
    __syncthreads();
#pragma unroll
    for (int j = 0; j < 16; j++) {
        int r = ty + j * 4;
        d[(size_t)(c0 + r) * 1024 + r0 + tx] = f2b(tile[tx][r]);
    }
}

// ---------------------------------------------------------------------------
// V transpose per (b,h): vtmp[bh][t][d] -> vt[bh][d][t]
// ---------------------------------------------------------------------------
__global__ __launch_bounds__(256) void transpose_v(
    const bf16* __restrict__ vtmp, bf16* __restrict__ vt)
{
    __shared__ bf16 tile[64][66];
    const int bh = blockIdx.y, t0 = blockIdx.x * 64;
    const int tx = threadIdx.x, ty = threadIdx.y;
    const bf16* src = vtmp + (size_t)bh * TT * HDIM;
    bf16* dst = vt + (size_t)bh * HDIM * TT;
#pragma unroll
    for (int j = 0; j < 16; j++) {
        int r = ty + j * 4;
        tile[r][tx] = src[(size_t)(t0 + r) * HDIM + tx];
    }
    __syncthreads();
#pragma unroll
    for (int j = 0; j < 16; j++) {
        int r = ty + j * 4;
        dst[(size_t)r * TT + t0 + tx] = tile[tx][r];
    }
}

// ---------------------------------------------------------------------------
// QKV GEMM: C = xb(8192x1024) * wqkvT(3072x1024)^T, tile 128x128x32.
// ---------------------------------------------------------------------------
__global__ __launch_bounds__(256) void gemm_qkv(
    const bf16* __restrict__ A, const bf16* __restrict__ BT,
    const float* __restrict__ bq, const float* __restrict__ bk,
    const float* __restrict__ bv,
    bf16* __restrict__ qo, bf16* __restrict__ ko, bf16* __restrict__ vo)
{
    __shared__ __align__(16) bf16 At[128 * 32];
    __shared__ __align__(16) bf16 Bt[128 * 32];
    const int tid  = threadIdx.x;
    const int lane = tid & 63, wave = tid >> 6;
    const int quad = lane >> 4, c = lane & 15;
    const int wm = wave >> 1, wn = wave & 1;
    const int m0 = blockIdx.y * 128, n0 = blockIdx.x * 128;
    const int K = 1024;
    const int chunkrow = lane >> 2;
    const int kseg     = (lane & 3) * 8;

    v4f acc[4][4];
#pragma unroll
    for (int i = 0; i < 4; i++)
#pragma unroll
        for (int j = 0; j < 4; j++) acc[i][j] = (v4f){0.f, 0.f, 0.f, 0.f};

    for (int k0 = 0; k0 < K; k0 += 32) {
#pragma unroll
        for (int ch = 0; ch < 2; ch++) {
            const int chunk = wave * 2 + ch;
            const int row   = chunk * 16 + chunkrow;
            GLDS16(At + chunk * 512, A  + (size_t)(m0 + row) * K + k0 + kseg);
            GLDS16(Bt + chunk * 512, BT + (size_t)(n0 + row) * K + k0 + kseg);
        }
        asm volatile("s_waitcnt vmcnt(0)" ::: "memory");
        __syncthreads();

        v8s af[4], bfr[4];
#pragma unroll
        for (int mt = 0; mt < 4; mt++)
            af[mt] = *(const v8s*)(At + (wm * 64 + mt * 16 + c) * 32 + quad * 8);
#pragma unroll
        for (int nt = 0; nt < 4; nt++)
            bfr[nt] = *(const v8s*)(Bt + (wn * 64 + nt * 16 + c) * 32 + quad * 8);
#pragma unroll
        for (int mt = 0; mt < 4; mt++)
#pragma unroll
            for (int nt = 0; nt < 4; nt++)
                acc[mt][nt] = mfma16x16x32(af[mt], bfr[nt], acc[mt][nt]);
        __syncthreads();
    }

#pragma unroll
    for (int mt = 0; mt < 4; mt++)
#pragma unroll
        for (int nt = 0; nt < 4; nt++) {
            const int col    = n0 + wn * 64 + nt * 16 + c;   // 0..3071
            const int type   = col >> 10;
            const int within = col & 1023;
            const int h = within >> 6, d = within & 63;
            const float* bp = (type == 0) ? bq : (type == 1) ? bk : bv;
            const float bias = bp[within];
#pragma unroll
            for (int r = 0; r < 4; r++) {
                const int row = m0 + wm * 64 + mt * 16 + quad * 4 + r;
                const int b_ = row >> 11, t = row & 2047;
                const int bh = b_ * HH + h;
                float v = acc[mt][nt][r] + bias;
                size_t idx = ((size_t)bh * TT + t) * HDIM + d;
                if (type == 0)      qo[idx] = f2b(v * QSCALE);
                else if (type == 1) ko[idx] = f2b(v);
                else                vo[idx] = f2b(v);
            }
        }
}

// ---------------------------------------------------------------------------
// Output GEMM: out = ctx(8192x1024) * woT(1024x1024)^T + bo, fp32 out.
// ---------------------------------------------------------------------------
__global__ __launch_bounds__(256) void gemm_out(
    const bf16* __restrict__ A, const bf16* __restrict__ BT,
    const float* __restrict__ bo, float* __restrict__ out)
{
    __shared__ __align__(16) bf16 At[128 * 32];
    __shared__ __align__(16) bf16 Bt[128 * 32];
    const int tid  = threadIdx.x;
    const int lane = tid & 63, wave = tid >> 6;
    const int quad = lane >> 4, c = lane & 15;
    const int wm = wave >> 1, wn = wave & 1;
    const int m0 = blockIdx.y * 128, n0 = blockIdx.x * 128;
    const int K = 1024;
    const int chunkrow = lane >> 2;
    const int kseg     = (lane & 3) * 8;

    v4f acc[4][4];
#pragma unroll
    for (int i = 0; i < 4; i++)
#pragma unroll
        for (int j = 0; j < 4; j++) acc[i][j] = (v4f){0.f, 0.f, 0.f, 0.f};

    for (int k0 = 0; k0 < K; k0 += 32) {
#pragma unroll
        for (int ch = 0; ch < 2; ch++) {
            const int chunk = wave * 2 + ch;
            const int row   = chunk * 16 + chunkrow;
            GLDS16(At + chunk * 512, A  + (size_t)(m0 + row) * K + k0 + kseg);
            GLDS16(Bt + chunk * 512, BT + (size_t)(n0 + row) * K + k0 + kseg);
        }
        asm volatile("s_waitcnt vmcnt(0)" ::: "memory");
        __syncthreads();

        v8s af[4], bfr[4];
#pragma unroll
        for (int mt = 0; mt < 4; mt++)
            af[mt] = *(const v8s*)(At + (wm * 64 + mt * 16 + c) * 32 + quad * 8);
#pragma unroll
        for (int nt = 0; nt < 4; nt++)
            bfr[nt] = *(const v8s*)(Bt + (wn * 64 + nt * 16 + c) * 32 + quad * 8);
#pragma unroll
        for (int mt = 0; mt < 4; mt++)
#pragma unroll
            for (int nt = 0; nt < 4; nt++)
                acc[mt][nt] = mfma16x16x32(af[mt], bfr[nt], acc[mt][nt]);
        __syncthreads();
    }

#pragma unroll
    for (int mt = 0; mt < 4; mt++)
#pragma unroll
        for (int nt = 0; nt < 4; nt++) {
            const int col = n0 + wn * 64 + nt * 16 + c;
            const float bias = bo[col];
#pragma unroll
            for (int r = 0; r < 4; r++) {
                const int row = m0 + wm * 64 + mt * 16 + quad * 4 + r;
                out[(size_t)row * 1024 + col] = acc[mt][nt][r] + bias;
            }
        }
}

// ---------------------------------------------------------------------------
// Flash attention v5: m97-style DMA pipeline.
// Block = (bh, 128-row q-group); 4 waves x 32 rows (2 tiles of 16).
// Per 32-key chunk: K tile (32x64) + V tile (64x32) staged to LDS via
// global_load_lds (2 issues/wave), double-buffered; loop shape
//   ds_read frags -> stage(i+1) -> compute -> vmcnt(0) -> raw s_barrier
// so DMA latency is hidden behind compute (one barrier per chunk).
// LDS layouts XOR-swizzled (on the DMA *source* address) so all b128
// fragment reads are optimal 8-phase.
// Chunk types: 0 = unmasked (full), 1 = xt diag (bq==bk), 2 = xt/x0
// boundary (bk<bq), 3 = x0 boundary (bk<=bq); bk via float reciprocal.
// grid 1024 = 64 bh x 16 groups (heavy groups first within each bh).
// ---------------------------------------------------------------------------
__global__ __launch_bounds__(256, 3) void attn(
    const bf16* __restrict__ Q, const bf16* __restrict__ Kb,
    const bf16* __restrict__ VT, bf16* __restrict__ ctx,
    const int* __restrict__ bsp)
{
    __shared__ __align__(16) bf16 Kt[2][32 * 64];
    __shared__ __align__(16) bf16 Vt[2][64 * 32];
    __shared__ __align__(16) bf16 plds[4][16][32];

    const int bs = bsp[0];
    const float inv  = 1.0f / (float)bs;
    const float hinv = 0.5f * inv;
    const int tid = threadIdx.x, lane = tid & 63, wv = tid >> 6;
    const int quad = lane >> 4, c = lane & 15;
    const int bh = blockIdx.x >> 4;
    const int j  = blockIdx.x & 15;
    const bool xt = j < 8;
    const int g  = xt ? (7 - j) : (15 - j);        // heavy groups dispatch first
    const int q0g = (xt ? 0 : NN) + g * 128;

    const bf16* qp = Q  + (size_t)bh * TT * HDIM;
    const bf16* kp = Kb + (size_t)bh * TT * HDIM;
    const bf16* vp = VT + (size_t)bh * HDIM * TT;

    // ---- chunk segments (block-uniform) -----------------------------------
    int d_lo = 0, nd = 0, nf = 0, b_lo = 0, nb = 0;
    if (xt) {
        d_lo = (bs * (q0g / bs)) & ~31;
        const int d_hi = min((bs * ((q0g + 127) / bs) + bs + 31) & ~31, NN);
        nd = (d_hi - d_lo) >> 5;
        const int f = bs * (q0g / bs);              // x0 keys kl < f: full
        nf = f >> 5;
        b_lo = NN + (nf << 5);
        const int b_hi = NN + min((bs * ((q0g + 127) / bs) + 31) & ~31, NN);
        nb = (b_hi > b_lo) ? (b_hi - b_lo) >> 5 : 0;
    } else {
        const int q0l = q0g - NN;
        const int f = min(bs * (q0l / bs) + bs, NN); // kl < f: full
        nf = f >> 5;
        b_lo = NN + (nf << 5);
        const int b_hi = NN + min((bs * ((q0l + 127) / bs) + bs + 31) & ~31, NN);
        nb = (b_hi > b_lo) ? (b_hi - b_lo) >> 5 : 0;
    }
    const int nc = nd + nf + nb;

    // ---- per-row block indices (float, exact for small ints) --------------
    float bqv[2][4];
#pragma unroll
    for (int t = 0; t < 2; t++)
#pragma unroll
        for (int r = 0; r < 4; r++) {
            const int qrow = q0g + wv * 32 + t * 16 + quad * 4 + r;
            const int qloc = xt ? qrow : qrow - NN;
            bqv[t][r] = floorf(fmaf((float)qloc, inv, hinv));
        }

    // ---- Q fragments -------------------------------------------------------
    v8s aq[2][2];
#pragma unroll
    for (int t = 0; t < 2; t++) {
        const int rowb = q0g + wv * 32 + t * 16;
        aq[t][0] = *(const v8s*)(qp + (size_t)(rowb + c) * HDIM + quad * 8);
        aq[t][1] = *(const v8s*)(qp + (size_t)(rowb + c) * HDIM + 32 + quad * 8);
    }

    v4f O[2][4];
#pragma unroll
    for (int t = 0; t < 2; t++)
#pragma unroll
        for (int dt = 0; dt < 4; dt++) O[t][dt] = (v4f){0.f, 0.f, 0.f, 0.f};
    float lr[2][4] = {{0.f,0.f,0.f,0.f},{0.f,0.f,0.f,0.f}};

    // ---- DMA source bases (content-swizzled; LDS dest is lane-ordered) ----
    const int klrow = lane >> 3, ks8 = lane & 7;           // K: 8 rows/wave
    const bf16* kSrc0 = kp + (size_t)(wv * 8 + klrow) * HDIM + ((ks8 ^ klrow) << 3);
    const int vlrow = lane >> 2, vs8 = lane & 3;           // V: 16 rows/wave
    const bf16* vSrc0 = vp + (size_t)(wv * 16 + vlrow) * TT + ((vs8 ^ (vlrow & 3)) << 3);

    auto kb_of = [&](int i, int& kb, int& type) {
        if (i < nd)           { kb = d_lo + (i << 5);            type = 1; }
        else if (i < nd + nf) { kb = NN + ((i - nd) << 5);       type = 0; }
        else                  { kb = b_lo + ((i - nd - nf) << 5); type = xt ? 2 : 3; }
    };
    auto stage = [&](int i) {
        int kb, ty; kb_of(i, kb, ty);
        const int sel = i & 1;
        GLDS16(&Kt[sel][wv * 512], kSrc0 + (size_t)kb * HDIM);
        GLDS16(&Vt[sel][wv * 512], vSrc0 + kb);
    };

    // ---- pipelined chunk loop ---------------------------------------------
    stage(0);
    asm volatile("s_waitcnt vmcnt(0)" ::: "memory");
    asm volatile("s_barrier" ::: "memory");

    const int xk = c & 7, xv = c & 3;
#pragma unroll 1
    for (int i = 0; i < nc; i++) {
        int kb, type; kb_of(i, kb, type);
        const int sel = i & 1;
        const bf16* Kl = Kt[sel];
        const bf16* Vl = Vt[sel];

        // fragment reads from the completed buffer
        const v8s k0a = *(const v8s*)(Kl + c * 64        + ((quad       ^ xk) << 3));
        const v8s k0b = *(const v8s*)(Kl + c * 64        + (((quad ^ 4) ^ xk) << 3));
        const v8s k1a = *(const v8s*)(Kl + (16 + c) * 64 + ((quad       ^ xk) << 3));
        const v8s k1b = *(const v8s*)(Kl + (16 + c) * 64 + (((quad ^ 4) ^ xk) << 3));
        v8s vf[4];
#pragma unroll
        for (int dt = 0; dt < 4; dt++)
            vf[dt] = *(const v8s*)(Vl + (dt * 16 + c) * 32 + ((quad ^ xv) << 3));

        // prefetch next chunk into the other buffer (overlaps compute)
        if (i + 1 < nc) stage(i + 1);

        // per-chunk key block indices for masking
        float bkA = 0.f, bkB = 0.f;
        if (type) {
            const int off = (type == 1) ? 0 : NN;
            bkA = floorf(fmaf((float)(kb + c - off),      inv, hinv));
            bkB = floorf(fmaf((float)(kb + 16 + c - off), inv, hinv));
        }

#pragma unroll
        for (int t = 0; t < 2; t++) {
            v4f Sa = (v4f){0.f, 0.f, 0.f, 0.f};
            v4f Sb = (v4f){0.f, 0.f, 0.f, 0.f};
            Sa = mfma16x16x32(aq[t][0], k0a, Sa);
            Sa = mfma16x16x32(aq[t][1], k0b, Sa);
            Sb = mfma16x16x32(aq[t][0], k1a, Sb);
            Sb = mfma16x16x32(aq[t][1], k1b, Sb);
#pragma unroll
            for (int r = 0; r < 4; r++) {
                float sa = Sa[r], sb = Sb[r];
                if (type == 1) {
                    if (bkA != bqv[t][r]) sa = MASKV;
                    if (bkB != bqv[t][r]) sb = MASKV;
                } else if (type == 2) {
                    if (!(bkA < bqv[t][r])) sa = MASKV;
                    if (!(bkB < bqv[t][r])) sb = MASKV;
                } else if (type == 3) {
                    if (!(bkA <= bqv[t][r])) sa = MASKV;
                    if (!(bkB <= bqv[t][r])) sb = MASKV;
                }
                const float pa = EXP2F(sa);
                const float pb = EXP2F(sb);
                lr[t][r] += pa + pb;
                plds[wv][quad * 4 + r][c]      = f2b(pa);
                plds[wv][quad * 4 + r][16 + c] = f2b(pb);
            }
            asm volatile("s_waitcnt lgkmcnt(0)" ::: "memory");
            const v8s pf = *(const v8s*)(&plds[wv][c][quad * 8]);
#pragma unroll
            for (int dt = 0; dt < 4; dt++)
                O[t][dt] = mfma16x16x32(pf, vf[dt], O[t][dt]);
        }

        // next buffer's DMA must be complete before anyone reads it, and all
        // waves must be done with this buffer before it is restaged.
        asm volatile("s_waitcnt vmcnt(0)" ::: "memory");
        asm volatile("s_barrier" ::: "memory");
    }

    // ---- denominator + ctx write ------------------------------------------
    const int b_ = bh >> 4, h = bh & 15;
#pragma unroll
    for (int t = 0; t < 2; t++)
#pragma unroll
        for (int r = 0; r < 4; r++) {
            float s = lr[t][r];
#pragma unroll
            for (int off = 1; off < 16; off <<= 1) s += __shfl_xor(s, off);
            const float invl = 1.0f / fmaxf(s, 1e-30f);
            const int trow = q0g + wv * 32 + t * 16 + quad * 4 + r;
#pragma unroll
            for (int dt = 0; dt < 4; dt++)
                ctx[((size_t)(b_ * TT + trow)) * DD + h * 64 + dt * 16 + c] =
                    f2b(O[t][dt][r] * invl);
        }
}

// ---------------------------------------------------------------------------
extern "C" void kernel_launch(void* const* d_in, const int* in_sizes, int n_in,
                              void* d_out, int out_size, void* d_ws, size_t ws_size,
                              hipStream_t stream)
{
    const float* x  = (const float*)d_in[0];
    const float* Wq = (const float*)d_in[1];
    const float* bq = (const float*)d_in[2];
    const float* Wk = (const float*)d_in[3];
    const float* bk = (const float*)d_in[4];
    const float* Wv = (const float*)d_in[5];
    const float* bv = (const float*)d_in[6];
    const float* Wo = (const float*)d_in[7];
    const float* bo = (const float*)d_in[8];
    const int*  bsp = (const int*)d_in[9];
    float* out = (float*)d_out;

    bf16* ws    = (bf16*)d_ws;
    bf16* xb    = ws;                           // reused as ctx after gemm_qkv
    bf16* wqkvT = xb + 8388608;
    bf16* woT   = wqkvT + 3 * 1024 * 1024;
    bf16* qbuf  = woT + 1024 * 1024;            // (bh,t,d)
    bf16* kbuf  = qbuf + 8388608;
    bf16* vtmp  = kbuf + 8388608;               // (bh,t,d)
    bf16* vt    = vtmp + 8388608;               // (bh,d,t)
    bf16* ctx   = xb;

    cast_x<<<8192, 256, 0, stream>>>(x, xb);
    transpose_w<<<dim3(16, 16, 4), dim3(64, 4), 0, stream>>>(Wq, Wk, Wv, Wo, wqkvT);
    gemm_qkv<<<dim3(24, 64), 256, 0, stream>>>(xb, wqkvT, bq, bk, bv,
                                               qbuf, kbuf, vtmp);
    transpose_v<<<dim3(32, 64), dim3(64, 4), 0, stream>>>(vtmp, vt);
    attn<<<1024, 256, 0, stream>>>(qbuf, kbuf, vt, ctx, bsp);
    gemm_out<<<dim3(8, 64), 256, 0, stream>>>(ctx, woT, bo, out);
}

// Round 7
// 251.689 us; speedup vs baseline: 1.4743x; 1.1288x over previous
//
#include <hip/hip_runtime.h>
#include <hip/hip_bf16.h>
#include <stdint.h>

typedef __hip_bfloat16 bf16;
typedef short v8s __attribute__((ext_vector_type(8)));
typedef float v4f __attribute__((ext_vector_type(4)));

// Shape fixed by setup_inputs: B=4, T=2048, D=1024, H=16, hd=64, n=1024.
#define TT   2048
#define DD   1024
#define HH   16
#define HDIM 64
#define NN   1024
#define MASKV (-1e9f)
// q scale = hd^-0.5 * log2(e): softmax p = exp2(score) == e^{qk/sqrt(hd)}
#define QSCALE 0.18033688011112042f

#if __has_builtin(__builtin_amdgcn_exp2f)
#define EXP2F(x) __builtin_amdgcn_exp2f(x)
#else
#define EXP2F(x) exp2f(x)
#endif

__device__ __forceinline__ v4f mfma16x16x32(v8s a, v8s b, v4f c) {
    return __builtin_amdgcn_mfma_f32_16x16x32_bf16(a, b, c, 0, 0, 0);
}

#define GLDS16(lds, g)                                                          \
    __builtin_amdgcn_global_load_lds(                                           \
        (const __attribute__((address_space(1))) void*)(g),                     \
        (__attribute__((address_space(3))) void*)(lds), 16, 0, 0)

__device__ __forceinline__ bf16 f2b(float f) { return __float2bfloat16(f); }

// ---------------------------------------------------------------------------
// x (fp32, 8192x1024) -> bf16
// ---------------------------------------------------------------------------
__global__ __launch_bounds__(256) void cast_x(const float* __restrict__ x,
                                              bf16* __restrict__ xb)
{
    const size_t i = ((size_t)blockIdx.x * 256 + threadIdx.x) * 4;
    const float4 f = *(const float4*)(x + i);
    union { bf16 b[4]; uint64_t u; } cv;
    cv.b[0] = f2b(f.x); cv.b[1] = f2b(f.y); cv.b[2] = f2b(f.z); cv.b[3] = f2b(f.w);
    *(uint64_t*)(xb + i) = cv.u;
}

// ---------------------------------------------------------------------------
// Transpose+cast 4x (1024x1024) fp32 weights -> bf16 dst[z*1M + n*1024 + k]
// ---------------------------------------------------------------------------
__global__ __launch_bounds__(256) void transpose_w(
    const float* __restrict__ w0, const float* __restrict__ w1,
    const float* __restrict__ w2, const float* __restrict__ w3,
    bf16* __restrict__ dst)
{
    __shared__ float tile[64][65];
    const float* src = (blockIdx.z == 0) ? w0 : (blockIdx.z == 1) ? w1
                      : (blockIdx.z == 2) ? w2 : w3;
    bf16* d = dst + (size_t)blockIdx.z * 1024 * 1024;
    const int r0 = blockIdx.y * 64, c0 = blockIdx.x * 64;
    const int tx = threadIdx.x, ty = threadIdx.y;
#pragma unroll
    for (int j = 0; j < 16; j++) {
        int r = ty + j * 4;
        tile[r][tx] = src[(size_t)(r0 + r) * 1024 + c0 + tx];
    }
    __syncthreads();
#pragma unroll
    for (int j = 0; j < 16; j++) {
        int r = ty + j * 4;
        d[(size_t)(c0 + r) * 1024 + r0 + tx] = f2b(tile[tx][r]);
    }
}

// ---------------------------------------------------------------------------
// V transpose per (b,h): vtmp[bh][t][d] -> vt[bh][d][t]
// ---------------------------------------------------------------------------
__global__ __launch_bounds__(256) void transpose_v(
    const bf16* __restrict__ vtmp, bf16* __restrict__ vt)
{
    __shared__ bf16 tile[64][66];
    const int bh = blockIdx.y, t0 = blockIdx.x * 64;
    const int tx = threadIdx.x, ty = threadIdx.y;
    const bf16* src = vtmp + (size_t)bh * TT * HDIM;
    bf16* dst = vt + (size_t)bh * HDIM * TT;
#pragma unroll
    for (int j = 0; j < 16; j++) {
        int r = ty + j * 4;
        tile[r][tx] = src[(size_t)(t0 + r) * HDIM + tx];
    }
    __syncthreads();
#pragma unroll
    for (int j = 0; j < 16; j++) {
        int r = ty + j * 4;
        dst[(size_t)r * TT + t0 + tx] = tile[tx][r];
    }
}

// ---------------------------------------------------------------------------
// QKV GEMM: C = xb(8192x1024) * wqkvT(3072x1024)^T, tile 128x128x32.
// Epilogue: type (q/k/v) is uniform per block (128-col tile within one type).
// ---------------------------------------------------------------------------
__global__ __launch_bounds__(256) void gemm_qkv(
    const bf16* __restrict__ A, const bf16* __restrict__ BT,
    const float* __restrict__ bq, const float* __restrict__ bk,
    const float* __restrict__ bv,
    bf16* __restrict__ qo, bf16* __restrict__ ko, bf16* __restrict__ vo)
{
    __shared__ __align__(16) bf16 At[128 * 32];
    __shared__ __align__(16) bf16 Bt[128 * 32];
    const int tid  = threadIdx.x;
    const int lane = tid & 63, wave = tid >> 6;
    const int quad = lane >> 4, c = lane & 15;
    const int wm = wave >> 1, wn = wave & 1;
    const int m0 = blockIdx.y * 128, n0 = blockIdx.x * 128;
    const int K = 1024;
    const int chunkrow = lane >> 2;
    const int kseg     = (lane & 3) * 8;

    v4f acc[4][4];
#pragma unroll
    for (int i = 0; i < 4; i++)
#pragma unroll
        for (int j = 0; j < 4; j++) acc[i][j] = (v4f){0.f, 0.f, 0.f, 0.f};

    for (int k0 = 0; k0 < K; k0 += 32) {
#pragma unroll
        for (int ch = 0; ch < 2; ch++) {
            const int chunk = wave * 2 + ch;
            const int row   = chunk * 16 + chunkrow;
            GLDS16(At + chunk * 512, A  + (size_t)(m0 + row) * K + k0 + kseg);
            GLDS16(Bt + chunk * 512, BT + (size_t)(n0 + row) * K + k0 + kseg);
        }
        asm volatile("s_waitcnt vmcnt(0)" ::: "memory");
        __syncthreads();

        v8s af[4], bfr[4];
#pragma unroll
        for (int mt = 0; mt < 4; mt++)
            af[mt] = *(const v8s*)(At + (wm * 64 + mt * 16 + c) * 32 + quad * 8);
#pragma unroll
        for (int nt = 0; nt < 4; nt++)
            bfr[nt] = *(const v8s*)(Bt + (wn * 64 + nt * 16 + c) * 32 + quad * 8);
#pragma unroll
        for (int mt = 0; mt < 4; mt++)
#pragma unroll
            for (int nt = 0; nt < 4; nt++)
                acc[mt][nt] = mfma16x16x32(af[mt], bfr[nt], acc[mt][nt]);
        __syncthreads();
    }

    // ---- branchless epilogue (type uniform per block) ----------------------
    const int type = n0 >> 10;
    bf16* o = (type == 0) ? qo : (type == 1) ? ko : vo;
    const float* bp = (type == 0) ? bq : (type == 1) ? bk : bv;
    const float scale = (type == 0) ? QSCALE : 1.0f;
    const int nbase = n0 & 1023;

#pragma unroll
    for (int mt = 0; mt < 4; mt++)
#pragma unroll
        for (int nt = 0; nt < 4; nt++) {
            const int within = nbase + wn * 64 + nt * 16 + c;
            const int h = within >> 6, d = within & 63;
            const float bias = bp[within];
#pragma unroll
            for (int r = 0; r < 4; r++) {
                const int row = m0 + wm * 64 + mt * 16 + quad * 4 + r;
                const int b_ = row >> 11, t = row & 2047;
                const int bh = b_ * HH + h;
                o[((size_t)bh * TT + t) * HDIM + d] =
                    f2b((acc[mt][nt][r] + bias) * scale);
            }
        }
}

// ---------------------------------------------------------------------------
// Output GEMM: out = ctx(8192x1024) * woT(1024x1024)^T + bo, fp32 out.
// ---------------------------------------------------------------------------
__global__ __launch_bounds__(256) void gemm_out(
    const bf16* __restrict__ A, const bf16* __restrict__ BT,
    const float* __restrict__ bo, float* __restrict__ out)
{
    __shared__ __align__(16) bf16 At[128 * 32];
    __shared__ __align__(16) bf16 Bt[128 * 32];
    const int tid  = threadIdx.x;
    const int lane = tid & 63, wave = tid >> 6;
    const int quad = lane >> 4, c = lane & 15;
    const int wm = wave >> 1, wn = wave & 1;
    const int m0 = blockIdx.y * 128, n0 = blockIdx.x * 128;
    const int K = 1024;
    const int chunkrow = lane >> 2;
    const int kseg     = (lane & 3) * 8;

    v4f acc[4][4];
#pragma unroll
    for (int i = 0; i < 4; i++)
#pragma unroll
        for (int j = 0; j < 4; j++) acc[i][j] = (v4f){0.f, 0.f, 0.f, 0.f};

    for (int k0 = 0; k0 < K; k0 += 32) {
#pragma unroll
        for (int ch = 0; ch < 2; ch++) {
            const int chunk = wave * 2 + ch;
            const int row   = chunk * 16 + chunkrow;
            GLDS16(At + chunk * 512, A  + (size_t)(m0 + row) * K + k0 + kseg);
            GLDS16(Bt + chunk * 512, BT + (size_t)(n0 + row) * K + k0 + kseg);
        }
        asm volatile("s_waitcnt vmcnt(0)" ::: "memory");
        __syncthreads();

        v8s af[4], bfr[4];
#pragma unroll
        for (int mt = 0; mt < 4; mt++)
            af[mt] = *(const v8s*)(At + (wm * 64 + mt * 16 + c) * 32 + quad * 8);
#pragma unroll
        for (int nt = 0; nt < 4; nt++)
            bfr[nt] = *(const v8s*)(Bt + (wn * 64 + nt * 16 + c) * 32 + quad * 8);
#pragma unroll
        for (int mt = 0; mt < 4; mt++)
#pragma unroll
            for (int nt = 0; nt < 4; nt++)
                acc[mt][nt] = mfma16x16x32(af[mt], bfr[nt], acc[mt][nt]);
        __syncthreads();
    }

#pragma unroll
    for (int mt = 0; mt < 4; mt++)
#pragma unroll
        for (int nt = 0; nt < 4; nt++) {
            const int col = n0 + wn * 64 + nt * 16 + c;
            const float bias = bo[col];
#pragma unroll
            for (int r = 0; r < 4; r++) {
                const int row = m0 + wm * 64 + mt * 16 + quad * 4 + r;
                out[(size_t)row * 1024 + col] = acc[mt][nt][r] + bias;
            }
        }
}

// ---------------------------------------------------------------------------
// Flash attention v6: v5's DMA pipeline + distribution-robust load balance
// + single LDS wait per chunk + quad-XOR P layout.
//
// bh = blockIdx & 63, j = blockIdx >> 6. CU classes stride by 256 blocks ->
// j strides by 4. The j->(xt,g) table makes every stride-4 class = 2 xt +
// 2 x0 groups with g-sum 14 -> per-CU work constant (~82 chunks).
// __launch_bounds__(256,4): all 4 blocks/CU co-resident (24 KB LDS each).
// ---------------------------------------------------------------------------
__global__ __launch_bounds__(256, 4) void attn(
    const bf16* __restrict__ Q, const bf16* __restrict__ Kb,
    const bf16* __restrict__ VT, bf16* __restrict__ ctx,
    const int* __restrict__ bsp)
{
    __shared__ __align__(16) bf16 Kt[2][32 * 64];
    __shared__ __align__(16) bf16 Vt[2][64 * 32];
    __shared__ __align__(16) bf16 plds[4][2][16 * 32];

    const int bs = bsp[0];
    const float inv  = 1.0f / (float)bs;
    const float hinv = 0.5f * inv;
    const int tid = threadIdx.x, lane = tid & 63, wv = tid >> 6;
    const int quad = lane >> 4, c = lane & 15;
    const int bh = blockIdx.x & 63;
    const int j  = blockIdx.x >> 6;                // 0..15
    // stride-4-balanced group table: classes {j,j+4,j+8,j+12} sum ~equal
    const int g_tbl[16] = {7,6,5,4, 0,1,2,3, 4,5,6,7, 3,2,1,0};
    const bool xt = j < 8;
    const int g  = g_tbl[j];
    const int q0g = (xt ? 0 : NN) + g * 128;

    const bf16* qp = Q  + (size_t)bh * TT * HDIM;
    const bf16* kp = Kb + (size_t)bh * TT * HDIM;
    const bf16* vp = VT + (size_t)bh * HDIM * TT;

    // ---- chunk segments (block-uniform) -----------------------------------
    int d_lo = 0, nd = 0, nf = 0, b_lo = 0, nb = 0;
    if (xt) {
        d_lo = (bs * (q0g / bs)) & ~31;
        const int d_hi = min((bs * ((q0g + 127) / bs) + bs + 31) & ~31, NN);
        nd = (d_hi - d_lo) >> 5;
        const int f = bs * (q0g / bs);              // x0 keys kl < f: full
        nf = f >> 5;
        b_lo = NN + (nf << 5);
        const int b_hi = NN + min((bs * ((q0g + 127) / bs) + 31) & ~31, NN);
        nb = (b_hi > b_lo) ? (b_hi - b_lo) >> 5 : 0;
    } else {
        const int q0l = q0g - NN;
        const int f = min(bs * (q0l / bs) + bs, NN); // kl < f: full
        nf = f >> 5;
        b_lo = NN + (nf << 5);
        const int b_hi = NN + min((bs * ((q0l + 127) / bs) + bs + 31) & ~31, NN);
        nb = (b_hi > b_lo) ? (b_hi - b_lo) >> 5 : 0;
    }
    const int nc = nd + nf + nb;

    // ---- per-row block indices (float, exact small ints) ------------------
    float bqv[2][4];
#pragma unroll
    for (int t = 0; t < 2; t++)
#pragma unroll
        for (int r = 0; r < 4; r++) {
            const int qrow = q0g + wv * 32 + t * 16 + quad * 4 + r;
            const int qloc = xt ? qrow : qrow - NN;
            bqv[t][r] = floorf(fmaf((float)qloc, inv, hinv));
        }

    // ---- Q fragments -------------------------------------------------------
    v8s aq[2][2];
#pragma unroll
    for (int t = 0; t < 2; t++) {
        const int rowb = q0g + wv * 32 + t * 16;
        aq[t][0] = *(const v8s*)(qp + (size_t)(rowb + c) * HDIM + quad * 8);
        aq[t][1] = *(const v8s*)(qp + (size_t)(rowb + c) * HDIM + 32 + quad * 8);
    }

    v4f O[2][4];
#pragma unroll
    for (int t = 0; t < 2; t++)
#pragma unroll
        for (int dt = 0; dt < 4; dt++) O[t][dt] = (v4f){0.f, 0.f, 0.f, 0.f};
    float lr[2][4] = {{0.f,0.f,0.f,0.f},{0.f,0.f,0.f,0.f}};

    // ---- DMA source bases (content-swizzled; LDS dest lane-ordered) -------
    const int klrow = lane >> 3, ks8 = lane & 7;           // K: 8 rows/wave
    const bf16* kSrc0 = kp + (size_t)(wv * 8 + klrow) * HDIM + ((ks8 ^ klrow) << 3);
    const int vlrow = lane >> 2, vs8 = lane & 3;           // V: 16 rows/wave
    const bf16* vSrc0 = vp + (size_t)(wv * 16 + vlrow) * TT + ((vs8 ^ (vlrow & 3)) << 3);

    auto kb_of = [&](int i, int& kb, int& type) {
        if (i < nd)           { kb = d_lo + (i << 5);             type = 1; }
        else if (i < nd + nf) { kb = NN + ((i - nd) << 5);        type = 0; }
        else                  { kb = b_lo + ((i - nd - nf) << 5); type = xt ? 2 : 3; }
    };
    auto stage = [&](int i) {
        int kb, ty; kb_of(i, kb, ty);
        const int sel = i & 1;
        GLDS16(&Kt[sel][wv * 512], kSrc0 + (size_t)kb * HDIM);
        GLDS16(&Vt[sel][wv * 512], vSrc0 + kb);
    };

    // ---- pipelined chunk loop ---------------------------------------------
    stage(0);
    asm volatile("s_waitcnt vmcnt(0)" ::: "memory");
    asm volatile("s_barrier" ::: "memory");

    const int xk = c & 7, xv = c & 3;
    const int pquad = quad << 3;                 // writer XOR mask (8*quad)
#pragma unroll 1
    for (int i = 0; i < nc; i++) {
        int kb, type; kb_of(i, kb, type);
        const int sel = i & 1;
        const bf16* Kl = Kt[sel];
        const bf16* Vl = Vt[sel];

        const v8s k0a = *(const v8s*)(Kl + c * 64        + ((quad       ^ xk) << 3));
        const v8s k0b = *(const v8s*)(Kl + c * 64        + (((quad ^ 4) ^ xk) << 3));
        const v8s k1a = *(const v8s*)(Kl + (16 + c) * 64 + ((quad       ^ xk) << 3));
        const v8s k1b = *(const v8s*)(Kl + (16 + c) * 64 + (((quad ^ 4) ^ xk) << 3));
        v8s vf[4];
#pragma unroll
        for (int dt = 0; dt < 4; dt++)
            vf[dt] = *(const v8s*)(Vl + (dt * 16 + c) * 32 + ((quad ^ xv) << 3));

        if (i + 1 < nc) stage(i + 1);           // overlap DMA with compute

        float bkA = 0.f, bkB = 0.f;
        if (type) {
            const int off = (type == 1) ? 0 : NN;
            bkA = floorf(fmaf((float)(kb + c - off),      inv, hinv));
            bkB = floorf(fmaf((float)(kb + 16 + c - off), inv, hinv));
        }

        // ---- scores + exp + P writes for BOTH tiles, then ONE wait --------
#pragma unroll
        for (int t = 0; t < 2; t++) {
            v4f Sa = (v4f){0.f, 0.f, 0.f, 0.f};
            v4f Sb = (v4f){0.f, 0.f, 0.f, 0.f};
            Sa = mfma16x16x32(aq[t][0], k0a, Sa);
            Sa = mfma16x16x32(aq[t][1], k0b, Sa);
            Sb = mfma16x16x32(aq[t][0], k1a, Sb);
            Sb = mfma16x16x32(aq[t][1], k1b, Sb);
            bf16* pw = &plds[wv][t][(quad * 4) * 32];
#pragma unroll
            for (int r = 0; r < 4; r++) {
                float sa = Sa[r], sb = Sb[r];
                if (type == 1) {
                    if (bkA != bqv[t][r]) sa = MASKV;
                    if (bkB != bqv[t][r]) sb = MASKV;
                } else if (type == 2) {
                    if (!(bkA < bqv[t][r])) sa = MASKV;
                    if (!(bkB < bqv[t][r])) sb = MASKV;
                } else if (type == 3) {
                    if (!(bkA <= bqv[t][r])) sa = MASKV;
                    if (!(bkB <= bqv[t][r])) sb = MASKV;
                }
                const float pa = EXP2F(sa);
                const float pb = EXP2F(sb);
                lr[t][r] += pa + pb;
                // quad-XOR layout: P[q][k] at q*32 + (k ^ 8*(q>>2))
                pw[r * 32 + (c ^ pquad)]        = f2b(pa);
                pw[r * 32 + ((c + 16) ^ pquad)] = f2b(pb);
            }
        }
        asm volatile("s_waitcnt lgkmcnt(0)" ::: "memory");
#pragma unroll
        for (int t = 0; t < 2; t++) {
            const v8s pf = *(const v8s*)(&plds[wv][t][c * 32 +
                                        ((quad ^ ((c >> 2) & 3)) << 3)]);
#pragma unroll
            for (int dt = 0; dt < 4; dt++)
                O[t][dt] = mfma16x16x32(pf, vf[dt], O[t][dt]);
        }

        asm volatile("s_waitcnt vmcnt(0)" ::: "memory");
        asm volatile("s_barrier" ::: "memory");
    }

    // ---- denominator + ctx write ------------------------------------------
    const int b_ = bh >> 4, h = bh & 15;
#pragma unroll
    for (int t = 0; t < 2; t++)
#pragma unroll
        for (int r = 0; r < 4; r++) {
            float s = lr[t][r];
#pragma unroll
            for (int off = 1; off < 16; off <<= 1) s += __shfl_xor(s, off);
            const float invl = 1.0f / fmaxf(s, 1e-30f);
            const int trow = q0g + wv * 32 + t * 16 + quad * 4 + r;
#pragma unroll
            for (int dt = 0; dt < 4; dt++)
                ctx[((size_t)(b_ * TT + trow)) * DD + h * 64 + dt * 16 + c] =
                    f2b(O[t][dt][r] * invl);
        }
}

// ---------------------------------------------------------------------------
extern "C" void kernel_launch(void* const* d_in, const int* in_sizes, int n_in,
                              void* d_out, int out_size, void* d_ws, size_t ws_size,
                              hipStream_t stream)
{
    const float* x  = (const float*)d_in[0];
    const float* Wq = (const float*)d_in[1];
    const float* bq = (const float*)d_in[2];
    const float* Wk = (const float*)d_in[3];
    const float* bk = (const float*)d_in[4];
    const float* Wv = (const float*)d_in[5];
    const float* bv = (const float*)d_in[6];
    const float* Wo = (const float*)d_in[7];
    const float* bo = (const float*)d_in[8];
    const int*  bsp = (const int*)d_in[9];
    float* out = (float*)d_out;

    bf16* ws    = (bf16*)d_ws;
    bf16* xb    = ws;                           // reused as ctx after gemm_qkv
    bf16* wqkvT = xb + 8388608;
    bf16* woT   = wqkvT + 3 * 1024 * 1024;
    bf16* qbuf  = woT + 1024 * 1024;            // (bh,t,d)
    bf16* kbuf  = qbuf + 8388608;
    bf16* vtmp  = kbuf + 8388608;               // (bh,t,d)
    bf16* vt    = vtmp + 8388608;               // (bh,d,t)
    bf16* ctx   = xb;

    cast_x<<<8192, 256, 0, stream>>>(x, xb);
    transpose_w<<<dim3(16, 16, 4), dim3(64, 4), 0, stream>>>(Wq, Wk, Wv, Wo, wqkvT);
    gemm_qkv<<<dim3(24, 64), 256, 0, stream>>>(xb, wqkvT, bq, bk, bv,
                                               qbuf, kbuf, vtmp);
    transpose_v<<<dim3(32, 64), dim3(64, 4), 0, stream>>>(vtmp, vt);
    attn<<<1024, 256, 0, stream>>>(qbuf, kbuf, vt, ctx, bsp);
    gemm_out<<<dim3(8, 64), 256, 0, stream>>>(ctx, woT, bo, out);
}